// Round 1
// baseline (576.554 us; speedup 1.0000x reference)
//
#include <hip/hip_runtime.h>
#include <hip/hip_bf16.h>

typedef __attribute__((ext_vector_type(8))) short short8;
typedef __attribute__((ext_vector_type(4))) float f32x4;
typedef __attribute__((ext_vector_type(4))) unsigned short ushort4_;
typedef __attribute__((ext_vector_type(2))) unsigned long ulong2_;

__device__ __forceinline__ unsigned short f2bf(float f) {
  unsigned u = __builtin_bit_cast(unsigned, f);
  u += 0x7fff + ((u >> 16) & 1);   // RNE
  return (unsigned short)(u >> 16);
}

// ---------------- sincos table: [s][i] -> (cos, sin), i in [0,128) ----------------
__global__ void sincos_kernel(float2* __restrict__ table) {
  int idx = blockIdx.x * 256 + threadIdx.x;     // 2048*128
  int s = idx >> 7, i = idx & 127;
  float inv = exp2f(-(float)i * (13.287712379549449f / 128.0f)); // 10000^(-i/128)
  float ang = (float)s * inv;
  table[idx] = make_float2(cosf(ang), sinf(ang));
}

// ---------------- fp32 -> bf16 elementwise (vectorized) ----------------
__global__ void convert_x_kernel(const float* __restrict__ in, unsigned short* __restrict__ out, int n4) {
  int idx = blockIdx.x * 256 + threadIdx.x;
  if (idx >= n4) return;
  float4 v = ((const float4*)in)[idx];
  ushort4_ o = { f2bf(v.x), f2bf(v.y), f2bf(v.z), f2bf(v.w) };
  *(ushort4_*)(out + (size_t)idx * 4) = o;
}

// ---------------- fp32 [R][C] -> bf16 [C][R] transpose ----------------
__global__ __launch_bounds__(256) void wtrans_kernel(const float* __restrict__ in,
                                                     unsigned short* __restrict__ out,
                                                     int R, int C) {
  __shared__ float t[32][33];
  int tx = threadIdx.x & 31, ty = threadIdx.x >> 5;
  int r0 = blockIdx.y * 32, c0 = blockIdx.x * 32;
#pragma unroll
  for (int k = 0; k < 4; ++k) t[ty + k * 8][tx] = in[(size_t)(r0 + ty + k * 8) * C + c0 + tx];
  __syncthreads();
#pragma unroll
  for (int k = 0; k < 4; ++k) out[(size_t)(c0 + ty + k * 8) * R + r0 + tx] = f2bf(t[tx][ty + k * 8]);
}

// ---------------- V slice of QKV fp32 -> bf16 [b*4+hk][256][2048] transposed ----------------
__global__ __launch_bounds__(256) void vtrans_kernel(const float* __restrict__ qkv,
                                                     unsigned short* __restrict__ Vt) {
  __shared__ float t[32][33];
  int z = blockIdx.z; int b = z >> 2, hk = z & 3;
  const float* in = qkv + (size_t)b * 2048 * 4096 + 3072 + hk * 256; // rows s (ld 4096), cols d
  unsigned short* out = Vt + (size_t)z * 256 * 2048;                 // [256][2048]
  int tx = threadIdx.x & 31, ty = threadIdx.x >> 5;
  int r0 = blockIdx.y * 32, c0 = blockIdx.x * 32;   // r0: s, c0: d
#pragma unroll
  for (int k = 0; k < 4; ++k) t[ty + k * 8][tx] = in[(size_t)(r0 + ty + k * 8) * 4096 + c0 + tx];
  __syncthreads();
#pragma unroll
  for (int k = 0; k < 4; ++k) out[(size_t)(c0 + ty + k * 8) * 2048 + r0 + tx] = f2bf(t[tx][ty + k * 8]);
}

// ---------------- RoPE: fp32 QKV -> bf16 Qb [b][h][s][256], Kb [b][hk][s][256] ----------------
__global__ void rope_kernel(const float* __restrict__ qkv, const float2* __restrict__ table,
                            unsigned short* __restrict__ Qb, unsigned short* __restrict__ Kb) {
  int idx = blockIdx.x * 256 + threadIdx.x;   // 2*2048*12*128
  int i = idx & 127;
  int rest = idx >> 7;
  int h12 = rest % 12;
  int rest2 = rest / 12;
  int s = rest2 & 2047;
  int b = rest2 >> 11;
  float2 cs = table[(s << 7) + i];
  size_t row = (size_t)b * 2048 + s;
  size_t col; unsigned short* out;
  if (h12 < 8) { col = (size_t)h12 * 256; out = Qb + (((size_t)(b * 8 + h12) * 2048 + s) << 8); }
  else { int hk = h12 - 8; col = 2048 + (size_t)hk * 256; out = Kb + (((size_t)(b * 4 + hk) * 2048 + s) << 8); }
  float x1 = qkv[row * 4096 + col + i];
  float x2 = qkv[row * 4096 + col + 128 + i];
  out[i]       = f2bf(x1 * cs.x - x2 * cs.y);
  out[128 + i] = f2bf(x2 * cs.x + x1 * cs.y);
}

// ---------------- bf16 GEMM-BT: C[M][N] = A[M][K] * Bt[N][K]^T (fp32 out) ----------------
__global__ __launch_bounds__(256) void gemm_bt_kernel(const unsigned short* __restrict__ A,
                                                      const unsigned short* __restrict__ Bt,
                                                      float* __restrict__ C, int M, int N, int K) {
  __shared__ unsigned short sA[128 * 32];
  __shared__ unsigned short sB[128 * 32];
  int tid = threadIdx.x;
  int lane = tid & 63, w = tid >> 6;
  int wr = w >> 1, wc = w & 1;
  int lr = lane & 15, lg = lane >> 4;
  long m0 = (long)blockIdx.x * 128, n0 = (long)blockIdx.y * 128;
  f32x4 acc[4][4] = {};
  int nkt = K >> 5;
  for (int kt = 0; kt < nkt; ++kt) {
    __syncthreads();
    long k0 = (long)kt * 32;
#pragma unroll
    for (int p = 0; p < 2; ++p) {
      int c = p * 256 + tid;                 // 512 chunks x 16B per matrix
      int row = c >> 2, colb = (c & 3) * 8;
      int dst = (c * 8) ^ ((row & 3) << 3);  // XOR swizzle (bank-conflict-free ds_read_b128)
      *(ulong2_*)&sA[dst] = *(const ulong2_*)&A[(m0 + row) * K + k0 + colb];
      *(ulong2_*)&sB[dst] = *(const ulong2_*)&Bt[(n0 + row) * K + k0 + colb];
    }
    __syncthreads();
    short8 af[4], bg[4];
#pragma unroll
    for (int mi = 0; mi < 4; ++mi) {
      int row = wr * 64 + mi * 16 + lr;
      int e = (row * 32 + lg * 8) ^ ((row & 3) << 3);
      af[mi] = *(const short8*)&sA[e];
    }
#pragma unroll
    for (int ni = 0; ni < 4; ++ni) {
      int row = wc * 64 + ni * 16 + lr;
      int e = (row * 32 + lg * 8) ^ ((row & 3) << 3);
      bg[ni] = *(const short8*)&sB[e];
    }
#pragma unroll
    for (int mi = 0; mi < 4; ++mi)
#pragma unroll
      for (int ni = 0; ni < 4; ++ni)
        acc[mi][ni] = __builtin_amdgcn_mfma_f32_16x16x32_bf16(af[mi], bg[ni], acc[mi][ni], 0, 0, 0);
  }
#pragma unroll
  for (int mi = 0; mi < 4; ++mi)
#pragma unroll
    for (int ni = 0; ni < 4; ++ni) {
      long r = m0 + wr * 64 + mi * 16 + lg * 4;
      long cc = n0 + wc * 64 + ni * 16 + lr;
#pragma unroll
      for (int i = 0; i < 4; ++i)
        C[(r + i) * N + cc] = acc[mi][ni][i];
    }
}

// ---------------- flash attention w/ tanh softcap, causal, GQA ----------------
// grid: (32 q-tiles, 16 b*h). 4 waves x 16 q-rows. KV tile = 64.
__global__ __launch_bounds__(256) void attn_kernel(const unsigned short* __restrict__ Qb,
                                                   const unsigned short* __restrict__ Kb,
                                                   const unsigned short* __restrict__ Vt,
                                                   unsigned short* __restrict__ attnb) {
  __shared__ unsigned short sK[64 * 256];   // [64][256] swizzled
  __shared__ unsigned short sV[256 * 64];   // [256][64] swizzled (V^T tile)
  __shared__ unsigned short sP[4][16 * 64]; // per-wave P
  int qt = blockIdx.x, bh = blockIdx.y;
  int b = bh >> 3, h = bh & 7, hk = h >> 1;
  const unsigned short* Qh = Qb + ((size_t)(b * 8 + h) << 19);
  const unsigned short* Kh = Kb + ((size_t)(b * 4 + hk) << 19);
  const unsigned short* Vh = Vt + ((size_t)(b * 4 + hk) << 19);
  int tid = threadIdx.x, w = tid >> 6, lane = tid & 63;
  int lr = lane & 15, lg = lane >> 4;

  short8 qf[8];
  int qrow = qt * 64 + w * 16 + lr;
#pragma unroll
  for (int kc = 0; kc < 8; ++kc)
    qf[kc] = *(const short8*)&Qh[(size_t)qrow * 256 + kc * 32 + lg * 8];

  f32x4 acc[16] = {};
  float m_i[4], l_i[4];
#pragma unroll
  for (int i = 0; i < 4; ++i) { m_i[i] = -1e30f; l_i[i] = 0.f; }
  int qbase = qt * 64 + w * 16 + lg * 4;   // + i = this lane's acc rows (global q pos)

  for (int kt2 = 0; kt2 <= qt; ++kt2) {
    __syncthreads();
#pragma unroll
    for (int p = 0; p < 8; ++p) {
      int c = p * 256 + tid;   // 2048 x 16B chunks each
      {
        int row = c >> 5;
        int dste = (c * 8) ^ ((row & 7) << 3);
        *(ulong2_*)&sK[dste] = *(const ulong2_*)&Kh[(size_t)kt2 * 16384 + (size_t)c * 8];
      }
      {
        int r = c >> 3, ccn = c & 7;
        int dste = (r * 64 + ccn * 8) ^ ((r & 7) << 3);
        *(ulong2_*)&sV[dste] = *(const ulong2_*)&Vh[(size_t)r * 2048 + kt2 * 64 + ccn * 8];
      }
    }
    __syncthreads();

    // S = Q K^T  (C-layout: row = lg*4+i, col = nf*16+lr)
    f32x4 sf[4] = {};
#pragma unroll
    for (int nf = 0; nf < 4; ++nf) {
#pragma unroll
      for (int kc = 0; kc < 8; ++kc) {
        int row = nf * 16 + lr;
        int e = (row * 256 + kc * 32 + lg * 8) ^ ((row & 7) << 3);
        short8 kfr = *(const short8*)&sK[e];
        sf[nf] = __builtin_amdgcn_mfma_f32_16x16x32_bf16(qf[kc], kfr, sf[nf], 0, 0, 0);
      }
    }

    // softcap + causal mask + online softmax (fp32)
    float pv[4][4];
    float pmax[4], psum[4];
#pragma unroll
    for (int i = 0; i < 4; ++i) pmax[i] = -1e30f;
    int kcol = kt2 * 64 + lr;
#pragma unroll
    for (int nf = 0; nf < 4; ++nf)
#pragma unroll
      for (int i = 0; i < 4; ++i) {
        float x = sf[nf][i] * (0.0625f / 50.0f);
        x = fminf(fmaxf(x, -10.f), 10.f);
        float e2 = __expf(2.f * x);
        float sc = 50.f * ((e2 - 1.f) * __builtin_amdgcn_rcpf(e2 + 1.f));
        bool masked = (kcol + nf * 16) > (qbase + i);
        sc = masked ? -1e30f : sc;
        pv[nf][i] = sc;
        pmax[i] = fmaxf(pmax[i], sc);
      }
#pragma unroll
    for (int d = 1; d < 16; d <<= 1)
#pragma unroll
      for (int i = 0; i < 4; ++i)
        pmax[i] = fmaxf(pmax[i], __shfl_xor(pmax[i], d));
    float scale_f[4];
#pragma unroll
    for (int i = 0; i < 4; ++i) {
      float m_new = fmaxf(m_i[i], pmax[i]);
      scale_f[i] = __expf(m_i[i] - m_new);
      m_i[i] = m_new;
      psum[i] = 0.f;
    }
#pragma unroll
    for (int nf = 0; nf < 4; ++nf)
#pragma unroll
      for (int i = 0; i < 4; ++i) {
        float p = __expf(pv[nf][i] - m_i[i]);
        pv[nf][i] = p;
        psum[i] += p;
      }
#pragma unroll
    for (int d = 1; d < 16; d <<= 1)
#pragma unroll
      for (int i = 0; i < 4; ++i)
        psum[i] += __shfl_xor(psum[i], d);
#pragma unroll
    for (int i = 0; i < 4; ++i)
      l_i[i] = l_i[i] * scale_f[i] + psum[i];
#pragma unroll
    for (int df = 0; df < 16; ++df)
#pragma unroll
      for (int i = 0; i < 4; ++i)
        acc[df][i] *= scale_f[i];

    // P -> LDS (C-layout write), reload as A-fragments
#pragma unroll
    for (int nf = 0; nf < 4; ++nf)
#pragma unroll
      for (int i = 0; i < 4; ++i)
        sP[w][(lg * 4 + i) * 64 + nf * 16 + lr] = f2bf(pv[nf][i]);
    asm volatile("s_waitcnt lgkmcnt(0)" ::: "memory");
    short8 pa[2];
#pragma unroll
    for (int kc2 = 0; kc2 < 2; ++kc2)
      pa[kc2] = *(const short8*)&sP[w][lr * 64 + kc2 * 32 + lg * 8];

    // O += P V   (B-frag from V^T tile rows = d)
#pragma unroll
    for (int df = 0; df < 16; ++df)
#pragma unroll
      for (int kc2 = 0; kc2 < 2; ++kc2) {
        int row = df * 16 + lr;
        int e = (row * 64 + kc2 * 32 + lg * 8) ^ ((row & 7) << 3);
        short8 vfr = *(const short8*)&sV[e];
        acc[df] = __builtin_amdgcn_mfma_f32_16x16x32_bf16(pa[kc2], vfr, acc[df], 0, 0, 0);
      }
  }

  float invl[4];
#pragma unroll
  for (int i = 0; i < 4; ++i) invl[i] = 1.0f / l_i[i];
  size_t mrow = (size_t)b * 2048 + qt * 64 + w * 16 + lg * 4;
#pragma unroll
  for (int df = 0; df < 16; ++df)
#pragma unroll
    for (int i = 0; i < 4; ++i)
      attnb[(mrow + i) * 2048 + h * 256 + df * 16 + lr] = f2bf(acc[df][i] * invl[i]);
}

extern "C" void kernel_launch(void* const* d_in, const int* in_sizes, int n_in,
                              void* d_out, int out_size, void* d_ws, size_t ws_size,
                              hipStream_t stream) {
  const float* hidden = (const float*)d_in[0];
  const float* wq = (const float*)d_in[1];
  const float* wk = (const float*)d_in[2];
  const float* wv = (const float*)d_in[3];
  const float* wo = (const float*)d_in[4];
  float* out = (float*)d_out;

  char* ws = (char*)d_ws;
  size_t off = 0;
  auto alloc = [&](size_t bytes) { void* p = ws + off; off += (bytes + 255) & ~255ULL; return p; };
  float2* table = (float2*)alloc((size_t)2048 * 128 * sizeof(float2));
  unsigned short* Xb    = (unsigned short*)alloc((size_t)4096 * 2304 * 2);
  unsigned short* WallT = (unsigned short*)alloc((size_t)4096 * 2304 * 2);
  unsigned short* WoT   = (unsigned short*)alloc((size_t)2304 * 2048 * 2);
  float*          QKV   = (float*)alloc((size_t)4096 * 4096 * 4);
  unsigned short* Qb    = (unsigned short*)alloc((size_t)2 * 8 * 2048 * 256 * 2);
  unsigned short* Kb    = (unsigned short*)alloc((size_t)2 * 4 * 2048 * 256 * 2);
  unsigned short* Vt    = (unsigned short*)alloc((size_t)2 * 4 * 2048 * 256 * 2);
  unsigned short* attnb = (unsigned short*)QKV;   // QKV is dead after rope+vtrans

  sincos_kernel<<<1024, 256, 0, stream>>>(table);
  convert_x_kernel<<<9216, 256, 0, stream>>>(hidden, Xb, 2359296);
  wtrans_kernel<<<dim3(64, 72), 256, 0, stream>>>(wq, WallT, 2304, 2048);
  wtrans_kernel<<<dim3(32, 72), 256, 0, stream>>>(wk, WallT + (size_t)2048 * 2304, 2304, 1024);
  wtrans_kernel<<<dim3(32, 72), 256, 0, stream>>>(wv, WallT + (size_t)3072 * 2304, 2304, 1024);
  wtrans_kernel<<<dim3(72, 64), 256, 0, stream>>>(wo, WoT, 2048, 2304);
  gemm_bt_kernel<<<dim3(32, 32), 256, 0, stream>>>(Xb, WallT, QKV, 4096, 4096, 2304);
  rope_kernel<<<24576, 256, 0, stream>>>(QKV, table, Qb, Kb);
  vtrans_kernel<<<dim3(8, 64, 8), 256, 0, stream>>>(QKV, Vt);
  attn_kernel<<<dim3(32, 16), 256, 0, stream>>>(Qb, Kb, Vt, attnb);
  gemm_bt_kernel<<<dim3(32, 18), 256, 0, stream>>>(attnb, WoT, out, 4096, 2304, 2048);
}

// Round 6
// 470.220 us; speedup vs baseline: 1.2261x; 1.2261x over previous
//
#include <hip/hip_runtime.h>
#include <hip/hip_bf16.h>

typedef __attribute__((ext_vector_type(8))) short short8;
typedef __attribute__((ext_vector_type(4))) float f32x4;
typedef __attribute__((ext_vector_type(4))) unsigned short ushort4_;
typedef __attribute__((ext_vector_type(2))) unsigned long ulong2_;

__device__ __forceinline__ unsigned short f2bf(float f) {
  unsigned u = __builtin_bit_cast(unsigned, f);
  u += 0x7fff + ((u >> 16) & 1);   // RNE
  return (unsigned short)(u >> 16);
}

__device__ __forceinline__ void gload16(const unsigned short* g, unsigned short* l) {
  __builtin_amdgcn_global_load_lds((const __attribute__((address_space(1))) unsigned int*)g,
                                   (__attribute__((address_space(3))) unsigned int*)l, 16, 0, 0);
}

// ---------------- sincos table: [s][i] -> (cos, sin), i in [0,128) ----------------
__global__ void sincos_kernel(float2* __restrict__ table) {
  int idx = blockIdx.x * 256 + threadIdx.x;     // 2048*128
  int s = idx >> 7, i = idx & 127;
  float inv = exp2f(-(float)i * (13.287712379549449f / 128.0f)); // 10000^(-i/128)
  float ang = (float)s * inv;
  table[idx] = make_float2(cosf(ang), sinf(ang));
}

// ---------------- fp32 -> bf16 elementwise (vectorized) ----------------
__global__ void convert_x_kernel(const float* __restrict__ in, unsigned short* __restrict__ out, int n4) {
  int idx = blockIdx.x * 256 + threadIdx.x;
  if (idx >= n4) return;
  float4 v = ((const float4*)in)[idx];
  ushort4_ o = { f2bf(v.x), f2bf(v.y), f2bf(v.z), f2bf(v.w) };
  *(ushort4_*)(out + (size_t)idx * 4) = o;
}

// ---------------- fp32 [R][C] -> bf16 [C][R] transpose ----------------
__global__ __launch_bounds__(256) void wtrans_kernel(const float* __restrict__ in,
                                                     unsigned short* __restrict__ out,
                                                     int R, int C) {
  __shared__ float t[32][33];
  int tx = threadIdx.x & 31, ty = threadIdx.x >> 5;
  int r0 = blockIdx.y * 32, c0 = blockIdx.x * 32;
#pragma unroll
  for (int k = 0; k < 4; ++k) t[ty + k * 8][tx] = in[(size_t)(r0 + ty + k * 8) * C + c0 + tx];
  __syncthreads();
#pragma unroll
  for (int k = 0; k < 4; ++k) out[(size_t)(c0 + ty + k * 8) * R + r0 + tx] = f2bf(t[tx][ty + k * 8]);
}

// ---------------- V slice of QKV fp32 -> bf16 [b*4+hk][256][2048] transposed ----------------
__global__ __launch_bounds__(256) void vtrans_kernel(const float* __restrict__ qkv,
                                                     unsigned short* __restrict__ Vt) {
  __shared__ float t[32][33];
  int z = blockIdx.z; int b = z >> 2, hk = z & 3;
  const float* in = qkv + (size_t)b * 2048 * 4096 + 3072 + hk * 256; // rows s (ld 4096), cols d
  unsigned short* out = Vt + (size_t)z * 256 * 2048;                 // [256][2048]
  int tx = threadIdx.x & 31, ty = threadIdx.x >> 5;
  int r0 = blockIdx.y * 32, c0 = blockIdx.x * 32;   // r0: s, c0: d
#pragma unroll
  for (int k = 0; k < 4; ++k) t[ty + k * 8][tx] = in[(size_t)(r0 + ty + k * 8) * 4096 + c0 + tx];
  __syncthreads();
#pragma unroll
  for (int k = 0; k < 4; ++k) out[(size_t)(c0 + ty + k * 8) * 2048 + r0 + tx] = f2bf(t[tx][ty + k * 8]);
}

// ---------------- RoPE: fp32 QKV -> bf16 Qb [b][h][s][256], Kb [b][hk][s][256] ----------------
__global__ void rope_kernel(const float* __restrict__ qkv, const float2* __restrict__ table,
                            unsigned short* __restrict__ Qb, unsigned short* __restrict__ Kb) {
  int idx = blockIdx.x * 256 + threadIdx.x;   // 2*2048*12*128
  int i = idx & 127;
  int rest = idx >> 7;
  int h12 = rest % 12;
  int rest2 = rest / 12;
  int s = rest2 & 2047;
  int b = rest2 >> 11;
  float2 cs = table[(s << 7) + i];
  size_t row = (size_t)b * 2048 + s;
  size_t col; unsigned short* out;
  if (h12 < 8) { col = (size_t)h12 * 256; out = Qb + (((size_t)(b * 8 + h12) * 2048 + s) << 8); }
  else { int hk = h12 - 8; col = 2048 + (size_t)hk * 256; out = Kb + (((size_t)(b * 4 + hk) * 2048 + s) << 8); }
  float x1 = qkv[row * 4096 + col + i];
  float x2 = qkv[row * 4096 + col + 128 + i];
  out[i]       = f2bf(x1 * cs.x - x2 * cs.y);
  out[128 + i] = f2bf(x2 * cs.x + x1 * cs.y);
}

// ---------------- bf16 GEMM-BT: C[M][N] = A[M][K] * Bt[N][K]^T (fp32 out) ----------------
// m97 structure: global_load_lds width-16, linear LDS, 2-barrier K-loop.
__global__ __launch_bounds__(256) void gemm_bt_kernel(const unsigned short* __restrict__ A,
                                                      const unsigned short* __restrict__ Bt,
                                                      float* __restrict__ C, int M, int N, int K) {
  __shared__ unsigned short sA[128 * 32];
  __shared__ unsigned short sB[128 * 32];
  int tid = threadIdx.x;
  int lane = tid & 63, w = tid >> 6;
  int wr = w >> 1, wc = w & 1;
  int lr = lane & 15, lg = lane >> 4;
  long m0 = (long)blockIdx.x * 128, n0 = (long)blockIdx.y * 128;
  f32x4 acc[4][4] = {};
  int nkt = K >> 5;
  for (int kt = 0; kt < nkt; ++kt) {
    __syncthreads();
    long k0 = (long)kt * 32;
#pragma unroll
    for (int p = 0; p < 2; ++p) {
      int c = p * 256 + tid;                 // 512 chunks x 16B per matrix
      int row = c >> 2, colb = (c & 3) * 8;
      gload16(&A[(m0 + row) * K + k0 + colb], &sA[c * 8]);
      gload16(&Bt[(n0 + row) * K + k0 + colb], &sB[c * 8]);
    }
    __syncthreads();   // compiler emits vmcnt(0) drain before barrier
    short8 af[4], bg[4];
#pragma unroll
    for (int mi = 0; mi < 4; ++mi)
      af[mi] = *(const short8*)&sA[(wr * 64 + mi * 16 + lr) * 32 + lg * 8];
#pragma unroll
    for (int ni = 0; ni < 4; ++ni)
      bg[ni] = *(const short8*)&sB[(wc * 64 + ni * 16 + lr) * 32 + lg * 8];
#pragma unroll
    for (int mi = 0; mi < 4; ++mi)
#pragma unroll
      for (int ni = 0; ni < 4; ++ni)
        acc[mi][ni] = __builtin_amdgcn_mfma_f32_16x16x32_bf16(af[mi], bg[ni], acc[mi][ni], 0, 0, 0);
  }
#pragma unroll
  for (int mi = 0; mi < 4; ++mi)
#pragma unroll
    for (int ni = 0; ni < 4; ++ni) {
      long r = m0 + wr * 64 + mi * 16 + lg * 4;
      long cc = n0 + wc * 64 + ni * 16 + lr;
#pragma unroll
      for (int i = 0; i < 4; ++i)
        C[(r + i) * N + cc] = acc[mi][ni][i];
    }
}

// ---------------- flash attention w/ tanh softcap, causal, GQA, 2-way KV split ----------------
// grid: (16 bh, 64 work). work y: qt = 31-(y>>1), s = y&1 (longest-first dispatch).
// Writes UNNORMALIZED partial O (fp32) + per-row (m,l); combine_kernel finishes.
__global__ __launch_bounds__(256) void attn_kernel(const unsigned short* __restrict__ Qb,
                                                   const unsigned short* __restrict__ Kb,
                                                   const unsigned short* __restrict__ Vt,
                                                   float* __restrict__ Op,
                                                   float* __restrict__ ml) {
  __shared__ unsigned short sK[64 * 256];   // [64][256] swizzled
  __shared__ unsigned short sV[256 * 64];   // [256][64] swizzled (V^T tile)
  __shared__ unsigned short sP[4][16 * 64]; // per-wave P
  int bh = blockIdx.x, y = blockIdx.y;
  int qt = 31 - (y >> 1), s = y & 1;
  int ntile = qt + 1, half = (ntile + 1) >> 1;
  int k0t = s ? half : 0, k1t = s ? ntile : half;
  int b = bh >> 3, h = bh & 7, hk = h >> 1;
  const unsigned short* Qh = Qb + ((size_t)(b * 8 + h) << 19);
  const unsigned short* Kh = Kb + ((size_t)(b * 4 + hk) << 19);
  const unsigned short* Vh = Vt + ((size_t)(b * 4 + hk) << 19);
  int tid = threadIdx.x, w = tid >> 6, lane = tid & 63;
  int lr = lane & 15, lg = lane >> 4;

  short8 qf[8];
  int qrow = qt * 64 + w * 16 + lr;
#pragma unroll
  for (int kc = 0; kc < 8; ++kc)
    qf[kc] = *(const short8*)&Qh[(size_t)qrow * 256 + kc * 32 + lg * 8];

  f32x4 acc[16] = {};
  float m_i[4], l_i[4];
#pragma unroll
  for (int i = 0; i < 4; ++i) { m_i[i] = -1e30f; l_i[i] = 0.f; }
  int qbase = qt * 64 + w * 16 + lg * 4;   // + i = this lane's acc rows (global q pos)

  for (int kt2 = k0t; kt2 < k1t; ++kt2) {
    __syncthreads();
#pragma unroll
    for (int p = 0; p < 8; ++p) {
      int c = p * 256 + tid;   // 2048 x 16B chunks each
      {
        int row = c >> 5;
        int dste = (c * 8) ^ ((row & 7) << 3);
        *(ulong2_*)&sK[dste] = *(const ulong2_*)&Kh[(size_t)kt2 * 16384 + (size_t)c * 8];
      }
      {
        int r = c >> 3, ccn = c & 7;
        int dste = (r * 64 + ccn * 8) ^ ((r & 7) << 3);
        *(ulong2_*)&sV[dste] = *(const ulong2_*)&Vh[(size_t)r * 2048 + kt2 * 64 + ccn * 8];
      }
    }
    __syncthreads();

    // S = Q K^T  (C-layout: row = lg*4+i, col = nf*16+lr)
    f32x4 sf[4] = {};
#pragma unroll
    for (int nf = 0; nf < 4; ++nf) {
#pragma unroll
      for (int kc = 0; kc < 8; ++kc) {
        int row = nf * 16 + lr;
        int e = (row * 256 + kc * 32 + lg * 8) ^ ((row & 7) << 3);
        short8 kfr = *(const short8*)&sK[e];
        sf[nf] = __builtin_amdgcn_mfma_f32_16x16x32_bf16(qf[kc], kfr, sf[nf], 0, 0, 0);
      }
    }

    // softcap + causal mask + online softmax (fp32)
    float pv[4][4];
    float pmax[4], psum[4];
#pragma unroll
    for (int i = 0; i < 4; ++i) pmax[i] = -1e30f;
    int kcol = kt2 * 64 + lr;
#pragma unroll
    for (int nf = 0; nf < 4; ++nf)
#pragma unroll
      for (int i = 0; i < 4; ++i) {
        float x = sf[nf][i] * (0.0625f / 50.0f);
        x = fminf(fmaxf(x, -10.f), 10.f);
        float e2 = __expf(2.f * x);
        float sc = 50.f * ((e2 - 1.f) * __builtin_amdgcn_rcpf(e2 + 1.f));
        bool masked = (kcol + nf * 16) > (qbase + i);
        sc = masked ? -1e30f : sc;
        pv[nf][i] = sc;
        pmax[i] = fmaxf(pmax[i], sc);
      }
#pragma unroll
    for (int d = 1; d < 16; d <<= 1)
#pragma unroll
      for (int i = 0; i < 4; ++i)
        pmax[i] = fmaxf(pmax[i], __shfl_xor(pmax[i], d));
    float scale_f[4];
#pragma unroll
    for (int i = 0; i < 4; ++i) {
      float m_new = fmaxf(m_i[i], pmax[i]);
      scale_f[i] = __expf(m_i[i] - m_new);
      m_i[i] = m_new;
      psum[i] = 0.f;
    }
#pragma unroll
    for (int nf = 0; nf < 4; ++nf)
#pragma unroll
      for (int i = 0; i < 4; ++i) {
        float p = __expf(pv[nf][i] - m_i[i]);
        pv[nf][i] = p;
        psum[i] += p;
      }
#pragma unroll
    for (int d = 1; d < 16; d <<= 1)
#pragma unroll
      for (int i = 0; i < 4; ++i)
        psum[i] += __shfl_xor(psum[i], d);
#pragma unroll
    for (int i = 0; i < 4; ++i)
      l_i[i] = l_i[i] * scale_f[i] + psum[i];
#pragma unroll
    for (int df = 0; df < 16; ++df)
#pragma unroll
      for (int i = 0; i < 4; ++i)
        acc[df][i] *= scale_f[i];

    // P -> LDS (C-layout write), reload as A-fragments
#pragma unroll
    for (int nf = 0; nf < 4; ++nf)
#pragma unroll
      for (int i = 0; i < 4; ++i)
        sP[w][(lg * 4 + i) * 64 + nf * 16 + lr] = f2bf(pv[nf][i]);
    asm volatile("s_waitcnt lgkmcnt(0)" ::: "memory");
    short8 pa[2];
#pragma unroll
    for (int kc2 = 0; kc2 < 2; ++kc2)
      pa[kc2] = *(const short8*)&sP[w][lr * 64 + kc2 * 32 + lg * 8];

    // O += P V   (B-frag from V^T tile rows = d)
#pragma unroll
    for (int df = 0; df < 16; ++df)
#pragma unroll
      for (int kc2 = 0; kc2 < 2; ++kc2) {
        int row = df * 16 + lr;
        int e = (row * 64 + kc2 * 32 + lg * 8) ^ ((row & 7) << 3);
        short8 vfr = *(const short8*)&sV[e];
        acc[df] = __builtin_amdgcn_mfma_f32_16x16x32_bf16(pa[kc2], vfr, acc[df], 0, 0, 0);
      }
  }

  // write unnormalized partial O + (m,l)
  size_t orow = (size_t)bh * 2048 + qbase;       // + i
#pragma unroll
  for (int df = 0; df < 16; ++df)
#pragma unroll
    for (int i = 0; i < 4; ++i)
      Op[(((orow + i) * 2 + s) << 8) + df * 16 + lr] = acc[df][i];
  if (lr == 0) {
#pragma unroll
    for (int i = 0; i < 4; ++i) {
      ml[(orow + i) * 4 + s * 2]     = m_i[i];
      ml[(orow + i) * 4 + s * 2 + 1] = l_i[i];
    }
  }
}

// ---------------- combine split-KV partials -> bf16 attn buffer ----------------
__global__ void combine_kernel(const float* __restrict__ Op, const float* __restrict__ ml,
                               unsigned short* __restrict__ attnb) {
  int idx = blockIdx.x * 256 + threadIdx.x;   // 16*2048*64
  int c4 = idx & 63;
  int rest = idx >> 6;                        // bh*2048 + row
  const float* mlp = ml + (size_t)rest * 4;
  float m0 = mlp[0], l0 = mlp[1], m1 = mlp[2], l1 = mlp[3];
  float m = fmaxf(m0, m1);
  float w0 = __expf(m0 - m), w1 = __expf(m1 - m);
  float inv = 1.0f / (l0 * w0 + l1 * w1);
  const float4 o0 = *(const float4*)&Op[(((size_t)rest * 2 + 0) << 8) + c4 * 4];
  const float4 o1 = *(const float4*)&Op[(((size_t)rest * 2 + 1) << 8) + c4 * 4];
  int row = rest & 2047, bh = rest >> 11;
  int b = bh >> 3, h = bh & 7;
  ushort4_ o;
  o.x = f2bf((o0.x * w0 + o1.x * w1) * inv);
  o.y = f2bf((o0.y * w0 + o1.y * w1) * inv);
  o.z = f2bf((o0.z * w0 + o1.z * w1) * inv);
  o.w = f2bf((o0.w * w0 + o1.w * w1) * inv);
  *(ushort4_*)&attnb[((size_t)(b * 2048 + row)) * 2048 + h * 256 + c4 * 4] = o;
}

extern "C" void kernel_launch(void* const* d_in, const int* in_sizes, int n_in,
                              void* d_out, int out_size, void* d_ws, size_t ws_size,
                              hipStream_t stream) {
  const float* hidden = (const float*)d_in[0];
  const float* wq = (const float*)d_in[1];
  const float* wk = (const float*)d_in[2];
  const float* wv = (const float*)d_in[3];
  const float* wo = (const float*)d_in[4];
  float* out = (float*)d_out;

  char* ws = (char*)d_ws;
  size_t off = 0;
  auto alloc = [&](size_t bytes) { void* p = ws + off; off += (bytes + 255) & ~255ULL; return p; };
  float2* table = (float2*)alloc((size_t)2048 * 128 * sizeof(float2));
  unsigned short* Xb    = (unsigned short*)alloc((size_t)4096 * 2304 * 2);
  unsigned short* WallT = (unsigned short*)alloc((size_t)4096 * 2304 * 2);
  unsigned short* WoT   = (unsigned short*)alloc((size_t)2304 * 2048 * 2);
  float*          QKV   = (float*)alloc((size_t)4096 * 4096 * 4);
  unsigned short* Qb    = (unsigned short*)alloc((size_t)2 * 8 * 2048 * 256 * 2);
  unsigned short* Kb    = (unsigned short*)alloc((size_t)2 * 4 * 2048 * 256 * 2);
  unsigned short* Vt    = (unsigned short*)alloc((size_t)2 * 4 * 2048 * 256 * 2);
  // aliases over dead regions:
  float*          Op    = QKV;                       // 2*16*2048*256 f32 == QKV bytes exactly
  float*          mlbuf = (float*)table;             // 1 MB <= 2 MB, table dead after rope
  unsigned short* attnb = Xb;                        // 16.8 MB <= 18.9 MB, Xb dead after gemm1

  sincos_kernel<<<1024, 256, 0, stream>>>(table);
  convert_x_kernel<<<9216, 256, 0, stream>>>(hidden, Xb, 2359296);
  wtrans_kernel<<<dim3(64, 72), 256, 0, stream>>>(wq, WallT, 2304, 2048);
  wtrans_kernel<<<dim3(32, 72), 256, 0, stream>>>(wk, WallT + (size_t)2048 * 2304, 2304, 1024);
  wtrans_kernel<<<dim3(32, 72), 256, 0, stream>>>(wv, WallT + (size_t)3072 * 2304, 2304, 1024);
  wtrans_kernel<<<dim3(72, 64), 256, 0, stream>>>(wo, WoT, 2048, 2304);
  gemm_bt_kernel<<<dim3(32, 32), 256, 0, stream>>>(Xb, WallT, QKV, 4096, 4096, 2304);
  rope_kernel<<<24576, 256, 0, stream>>>(QKV, table, Qb, Kb);
  vtrans_kernel<<<dim3(8, 64, 8), 256, 0, stream>>>(QKV, Vt);
  attn_kernel<<<dim3(16, 64), 256, 0, stream>>>(Qb, Kb, Vt, Op, mlbuf);
  combine_kernel<<<8192, 256, 0, stream>>>(Op, mlbuf, attnb);
  gemm_bt_kernel<<<dim3(32, 18), 256, 0, stream>>>(attnb, WoT, out, 4096, 2304, 2048);
}